// Round 16
// baseline (312.062 us; speedup 1.0000x reference)
//
#include <hip/hip_runtime.h>
#include <stdint.h>
#include <math.h>

// Problem constants (fixed by the reference)
#define NB    32          // graphs
#define NNODE 2048        // nodes per graph
#define EPB   16384       // edges per graph
#define NT    (NB*NNODE)  // 65536 total nodes
#define ETOT  (NB*EPB)    // 524288 edges
#define DF    128         // feature dim
#define KSEL  615         // ceil(0.3*2048)
#define EMAX  512         // LDS-staged edge cap per 32-row tile (mean 256)

typedef __attribute__((ext_vector_type(8))) short bf16x8;
typedef __attribute__((ext_vector_type(4))) float f32x4;

// ---- split-precision helpers: f32 ~= hi(bf16) + lo(bf16), err ~2^-17 ----
__device__ __forceinline__ unsigned short f2bf(float f){
  uint32_t u = __float_as_uint(f);
  u += 0x7FFFu + ((u>>16)&1u);                 // RNE
  return (unsigned short)(u>>16);
}
__device__ __forceinline__ void split2(float f, unsigned short& hi, unsigned short& lo){
  unsigned short h = f2bf(f);
  float fh = __uint_as_float(((uint32_t)h)<<16);
  hi = h;
  lo = f2bf(f - fh);
}
// monotone u32 <-> f32 (ascending u32 == ascending float over all reals)
__device__ __forceinline__ uint32_t f2mono(float f){
  uint32_t u = __float_as_uint(f);
  return (u & 0x80000000u) ? ~u : (u | 0x80000000u);
}
__device__ __forceinline__ float mono2f(uint32_t m){
  uint32_t u = (m & 0x80000000u) ? (m ^ 0x80000000u) : ~m;
  return __uint_as_float(u);
}

// ---------------- CSR build ----------------
// blocks 0..2047: degree count (global atomics). blocks 2048..2079: packB.
__global__ void k_deg(const int* __restrict__ edst, uint32_t* __restrict__ deg,
                      const float* __restrict__ Wl1, const float* __restrict__ Wr1,
                      const float* __restrict__ Wl2, const float* __restrict__ Wr2,
                      unsigned short* __restrict__ Bpk){
  const int bid = blockIdx.x;
  if (bid < ETOT/256){
    int e = bid*256 + threadIdx.x;
    int g = e >> 14;                           // EPB = 2^14
    atomicAdd(&deg[g*NNODE + edst[e]], 1u);
  } else {
    // weight pack: Bpk elem offset ks*8192 + ct*1024 + part*512 + lane*8 + j
    int tt = (bid - ETOT/256)*256 + threadIdx.x;   // 0..8191
    int layer = tt >> 12;
    int t2 = tt & 4095;
    const float* Wl = layer ? Wl2 : Wl1;
    const float* Wr = layer ? Wr2 : Wr1;
    unsigned short* B = Bpk + (size_t)layer*65536;
    int lane = t2 & 63;
    int ct   = (t2>>6) & 7;
    int ks   = (t2>>9) & 7;
    int c  = ct*16 + (lane & 15);
    int k0 = ks*32 + ((lane>>4)<<3);
    size_t base = ((size_t)((ks*8+ct)*2)*64 + lane)*8;
    #pragma unroll
    for (int j=0;j<8;++j){
      int k = k0 + j;
      float v = (k < DF) ? Wl[c*DF + k] : Wr[c*DF + (k-DF)];
      unsigned short h, l; split2(v, h, l);
      B[base + j]       = h;
      B[base + 512 + j] = l;
    }
  }
}

// per-graph exclusive scan of degrees (graphs independent: g*EPB base)
__global__ __launch_bounds__(256) void k_scanG(const uint32_t* __restrict__ deg,
                                               uint32_t* __restrict__ rowptr){
  __shared__ uint32_t wsum4[4];
  const int g = blockIdx.x, t = threadIdx.x;
  const int lane = t & 63, wid = t >> 6;
  const uint32_t* dg = deg + g*NNODE;
  uint32_t v[8]; const int b8 = t*8;
  uint32_t tsum = 0;
  #pragma unroll
  for (int j=0;j<8;++j){ v[j] = dg[b8+j]; tsum += v[j]; }
  uint32_t x = tsum;
  #pragma unroll
  for (int off=1; off<64; off<<=1){
    uint32_t y = __shfl_up(x, off, 64);
    if (lane >= off) x += y;
  }
  if (lane == 63) wsum4[wid] = x;
  __syncthreads();
  if (t == 0){
    uint32_t a = 0;
    #pragma unroll
    for (int w=0; w<4; ++w){ uint32_t tmp=wsum4[w]; wsum4[w]=a; a+=tmp; }
  }
  __syncthreads();
  uint32_t run = wsum4[wid] + x - tsum;        // thread-exclusive start
  uint32_t* rp = rowptr + g*NNODE + b8;
  #pragma unroll
  for (int j=0;j<8;++j){ rp[j] = g*EPB + run; run += v[j]; }
  if (g == 0 && t == 0) rowptr[NT] = ETOT;
}

// scatter edges into CSR order; col stored as u16 LOCAL node id
__global__ void k_scatter(const int* __restrict__ esrc, const int* __restrict__ edst,
                          const uint32_t* __restrict__ rowptr, uint32_t* __restrict__ deg,
                          unsigned short* __restrict__ colh){
  int e = blockIdx.x*256 + threadIdx.x;
  int g = e >> 14;
  int d = g*NNODE + edst[e];
  uint32_t old = atomicSub(&deg[d], 1u);
  colh[rowptr[d] + old - 1u] = (unsigned short)esrc[e];
}

// ---------------- fused SAGE layer: global_load_lds gather + MFMA ----------
// 128 threads = 2 waves, 32 rows/block; wave owns 16 contiguous rows.
// Phase 1: stage neighbor rows to an LDS ring via global_load_lds (4 instrs
// = 8 rows = 4KB per super-chunk; per-lane global src row + (lane&31)*16B,
// linear LDS dest), 2-deep pipeline with counted s_waitcnt vmcnt(4); wave-
// uniform edge walk consumes 8B/lane from the ring (conflict-free), flushes
// mean rows to smemA. Phase 2: 2 waves x 16 rows, K=256 split-bf16 MFMA.
// XCD swizzle: graph = bid&31.
template<int LAYER>
__global__ __launch_bounds__(128, 4) void k_sage(
    const float* __restrict__ Xin, const uint32_t* __restrict__ rowptr,
    const unsigned short* __restrict__ colh, const unsigned short* __restrict__ Bpk,
    const float* __restrict__ bias, float* __restrict__ OUT,
    const float* __restrict__ pw, float* __restrict__ scores)
{
  __shared__ float smemA[32][132];             // 16.9KB, +4 float pad per row
  __shared__ float ring[2][2][8][128];         // [wave][half][edge slot][feat] 16KB
  __shared__ unsigned short lcol[EMAX];        // 1KB staged local edge ids
  __shared__ uint32_t lrpl[33];                // tile-relative rowptr

  const int t = threadIdx.x;
  const int g = blockIdx.x & 31, jb = blockIdx.x >> 5;   // 64 blocks/graph
  const int rowBase = g*NNODE + jb*32;
  const float* Xg = Xin + (size_t)(g*NNODE)*DF;          // graph-local rows

  // ---- phase 0: stage CSR slice ----
  const uint32_t e0 = rowptr[rowBase];
  if (t < 33) lrpl[t] = rowptr[rowBase + t] - e0;
  const int ecnt = (int)(rowptr[rowBase + 32] - e0);
  for (int i=t; i<ecnt && i<EMAX; i+=128) lcol[i] = colh[e0+i];
  __syncthreads();

  // ---- phase 1: wave-level ring-staged gather ----
  const int w = t >> 6, lane = t & 63;
  {
    const int he = lane >> 5;                  // 0: even edge of pair, 1: odd
    const int qo = lane & 31;                  // 16B column within row
    int cur = w*16;
    const int segEnd = w*16 + 16;
    const uint32_t kb = lrpl[cur], ke = lrpl[segEnd];
    uint32_t rnext = lrpl[cur+1];
    float a0 = 0.f, a1 = 0.f;

    auto flushrow = [&](){
      uint32_t d = rnext - lrpl[cur];
      float invd = 1.0f / (float)(d ? d : 1u);
      *(float2*)&smemA[cur][lane*2] = make_float2(a0*invd, a1*invd);
      a0 = 0.f; a1 = 0.f;
      cur++;
      rnext = (cur < segEnd) ? lrpl[cur+1] : 0xFFFFFFFFu;
    };

    auto consume = [&](uint32_t ebase, int half){
      uint32_t eend = (ebase+8 < ke) ? ebase+8 : ke;
      for (uint32_t e=ebase; e<eend; ++e){
        float2 v = *(const float2*)&ring[w][half][e-ebase][lane*2];
        while (rnext <= e) flushrow();
        a0 += v.x; a1 += v.y;
      }
    };

    if (kb < ke){
      const bool fast = (ecnt <= EMAX);
      auto stage = [&](uint32_t ebase, int half){
        #pragma unroll
        for (int i=0;i<4;++i){
          uint32_t eidx = ebase + 2*i + he;
          uint32_t ecl = (eidx < ke) ? eidx : kb;          // clamp (kb valid)
          int s = fast ? (int)lcol[ecl] : (int)colh[e0+ecl];
          const float* gp = Xg + (size_t)s*DF + qo*4;
          __builtin_amdgcn_global_load_lds(
              (const __attribute__((address_space(1))) uint32_t*)gp,
              (__attribute__((address_space(3))) uint32_t*)&ring[w][half][2*i][0],
              16, 0, 0);
        }
      };
      const uint32_t nch = (ke - kb + 7u) >> 3;
      stage(kb, 0);
      for (uint32_t c=0; c<nch; ++c){
        int half = (int)(c & 1u);
        if (c+1 < nch){
          stage(kb + (c+1)*8, half^1);
          if (fast) asm volatile("s_waitcnt vmcnt(4)" ::: "memory");
          else      asm volatile("s_waitcnt vmcnt(0)" ::: "memory");
        } else {
          asm volatile("s_waitcnt vmcnt(0)" ::: "memory");
        }
        __builtin_amdgcn_sched_barrier(0);
        consume(kb + c*8, half);
      }
    }
    while (cur < segEnd) flushrow();           // trailing (incl. empty) rows
  }
  __syncthreads();

  // ---- phase 2: MFMA ----
  const int wid = w, l = lane;
  const int q = l >> 4, c16 = l & 15;
  const int arow = rowBase + wid*16 + c16;

  f32x4 own[8];                                // own row ks4..7
  #pragma unroll
  for (int ks4=0; ks4<4; ++ks4){
    const float* s = Xin + (size_t)arow*DF + ks4*32 + q*8;
    own[ks4*2]   = *(const f32x4*)s;
    own[ks4*2+1] = *(const f32x4*)(s+4);
  }

  f32x4 acc[8];
  #pragma unroll
  for (int ct=0; ct<8; ++ct) acc[ct] = (f32x4){0.f,0.f,0.f,0.f};

  #pragma unroll
  for (int ks=0; ks<8; ++ks){
    f32x4 A0, A1;
    if (ks < 4){
      const float* s = &smemA[wid*16 + c16][ks*32 + q*8];
      A0 = *(const f32x4*)s; A1 = *(const f32x4*)(s+4);
    } else {
      A0 = own[(ks-4)*2]; A1 = own[(ks-4)*2+1];
    }
    float v[8] = {A0.x,A0.y,A0.z,A0.w,A1.x,A1.y,A1.z,A1.w};
    bf16x8 ahi, alo;
    #pragma unroll
    for (int j=0;j<8;++j){
      unsigned short h, lo_; split2(v[j], h, lo_);
      ahi[j] = (short)h; alo[j] = (short)lo_;
    }
    const unsigned short* bp = Bpk + (size_t)ks*8192 + l*8;
    #pragma unroll
    for (int ct=0; ct<8; ++ct){
      bf16x8 bhi = *(const bf16x8*)(bp + ct*1024);
      bf16x8 blo = *(const bf16x8*)(bp + ct*1024 + 512);
      acc[ct] = __builtin_amdgcn_mfma_f32_16x16x32_bf16(ahi, bhi, acc[ct], 0,0,0);
      acc[ct] = __builtin_amdgcn_mfma_f32_16x16x32_bf16(ahi, blo, acc[ct], 0,0,0);
      acc[ct] = __builtin_amdgcn_mfma_f32_16x16x32_bf16(alo, bhi, acc[ct], 0,0,0);
    }
  }

  // ---- epilogue ----
  const int rowOut = rowBase + wid*16;
  if constexpr (LAYER==1){
    #pragma unroll
    for (int ct=0; ct<8; ++ct){
      int c = ct*16 + c16;
      float bv = bias[c];
      #pragma unroll
      for (int r=0; r<4; ++r){
        int grow = rowOut + q*4 + r;
        OUT[(size_t)grow*DF + c] = fmaxf(acc[ct][r] + bv, 0.f);
      }
    }
  } else {
    float ov[8][4];
    float pwv[8];
    float n2 = 0.f;
    #pragma unroll
    for (int ct=0; ct<8; ++ct){ pwv[ct] = pw[ct*16 + c16]; n2 += pwv[ct]*pwv[ct]; }
    n2 += __shfl_xor(n2,8,16); n2 += __shfl_xor(n2,4,16);
    n2 += __shfl_xor(n2,2,16); n2 += __shfl_xor(n2,1,16);
    float nrm = sqrtf(n2);
    #pragma unroll
    for (int ct=0; ct<8; ++ct){
      int c = ct*16 + c16;
      float bv = bias[c];
      #pragma unroll
      for (int r=0; r<4; ++r){
        int grow = rowOut + q*4 + r;
        float o = fmaxf(acc[ct][r] + bv, 0.f);
        OUT[(size_t)grow*DF + c] = o;
        ov[ct][r] = o;
      }
    }
    #pragma unroll
    for (int r=0; r<4; ++r){
      float p = 0.f;
      #pragma unroll
      for (int ct=0; ct<8; ++ct) p += ov[ct][r]*pwv[ct];
      p += __shfl_xor(p,8,16); p += __shfl_xor(p,4,16);
      p += __shfl_xor(p,2,16); p += __shfl_xor(p,1,16);
      if (c16 == 0) scores[rowOut + q*4 + r] = tanhf(p/nrm);
    }
  }
}

// ---------------- top-k via radix-select + pool + classifier ---------------
__global__ __launch_bounds__(1024) void k_topk(
    const float* __restrict__ scores, const float* __restrict__ H,
    const float* __restrict__ Wc1, const float* __restrict__ bc1,
    const float* __restrict__ Wc2, const float* __restrict__ bc2,
    float* __restrict__ out)
{
  __shared__ uint32_t keys[NNODE];            // 8KB monotone keys
  __shared__ uint32_t hist[64];
  __shared__ uint32_t wsum[16];               // block-scan wave sums
  __shared__ uint32_t sh_b, sh_rank, sh_cnt;
  __shared__ unsigned short selidx[KSEL+1];
  __shared__ float selval[KSEL+1];
  __shared__ float part[8*DF];
  __shared__ float emb[DF];
  __shared__ float hred[DF];

  const int t = threadIdx.x; const int b = blockIdx.x;
  const int lane = t & 63, wid = t >> 6;
  const float* sc = scores + b*NNODE;

  for (int i=t; i<NNODE; i+=1024) keys[i] = f2mono(sc[i]);
  __syncthreads();

  // ---- radix select: find threshold key T = 615th largest ----
  uint32_t prefix = 0, prefmask = 0, rank = KSEL, cntT = 0;
  #pragma unroll
  for (int lev=0; lev<6; ++lev){
    const int shift = (lev<5) ? (26 - 6*lev) : 0;
    const uint32_t bmask = (lev<5) ? 63u : 3u;
    if (t < 64) hist[t] = 0;
    __syncthreads();
    for (int i=t; i<NNODE; i+=1024){
      uint32_t k = keys[i];
      if ((k & prefmask) == prefix) atomicAdd(&hist[(k>>shift)&bmask], 1u);
    }
    __syncthreads();
    if (t < 64){
      uint32_t x = hist[t];
      #pragma unroll
      for (int off=1; off<64; off<<=1){        // inclusive suffix sum
        uint32_t y = __shfl_down(x, off, 64);
        if (t + off < 64) x += y;
      }
      uint32_t above = __shfl_down(x, 1, 64);
      if (t == 63) above = 0;
      if (above < rank && rank <= x){
        sh_b = (uint32_t)t; sh_rank = rank - above; sh_cnt = x - above;
      }
    }
    __syncthreads();
    prefix |= (sh_b << shift);
    prefmask |= (bmask << shift);
    rank = sh_rank; cntT = sh_cnt;
    __syncthreads();
  }
  const uint32_t T = prefix;
  const uint32_t m = rank;

  // ---- selection + compaction (block scans, shfl-based) ----
  uint32_t k0 = keys[2*t], k1 = keys[2*t+1];
  uint32_t eq0 = (k0 == T), eq1 = (k1 == T);
  uint32_t eqr0 = 0, eqr1 = 0;

  if (m != cntT){
    uint32_t v = eq0 + eq1, x = v;
    #pragma unroll
    for (int off=1; off<64; off<<=1){
      uint32_t y = __shfl_up(x, off, 64);
      if (lane >= off) x += y;
    }
    if (lane == 63) wsum[wid] = x;
    __syncthreads();
    if (wid == 0){
      uint32_t s = (lane < 16) ? wsum[lane] : 0;
      #pragma unroll
      for (int off=1; off<16; off<<=1){
        uint32_t y = __shfl_up(s, off, 64);
        if (lane >= off) s += y;
      }
      if (lane < 16) wsum[lane] = s;
    }
    __syncthreads();
    uint32_t excl = (wid ? wsum[wid-1] : 0) + x - v;
    eqr0 = excl; eqr1 = excl + eq0;
    __syncthreads();
  }

  uint32_t sel0 = (k0 > T) || (eq0 && eqr0 < m);
  uint32_t sel1 = (k1 > T) || (eq1 && eqr1 < m);
  {
    uint32_t v = sel0 + sel1, x = v;
    #pragma unroll
    for (int off=1; off<64; off<<=1){
      uint32_t y = __shfl_up(x, off, 64);
      if (lane >= off) x += y;
    }
    if (lane == 63) wsum[wid] = x;
    __syncthreads();
    if (wid == 0){
      uint32_t s = (lane < 16) ? wsum[lane] : 0;
      #pragma unroll
      for (int off=1; off<16; off<<=1){
        uint32_t y = __shfl_up(s, off, 64);
        if (lane >= off) s += y;
      }
      if (lane < 16) wsum[lane] = s;
    }
    __syncthreads();
    uint32_t excl = (wid ? wsum[wid-1] : 0) + x - v;
    if (sel0){ selidx[excl] = (unsigned short)(2*t);   selval[excl] = mono2f(k0); }
    if (sel1){ selidx[excl+sel0] = (unsigned short)(2*t+1); selval[excl+sel0] = mono2f(k1); }
  }
  __syncthreads();

  // ---- gated mean over the 615 selected rows (4-deep unrolled gather) ----
  const int pg = t >> 7, f = t & (DF-1);
  const float* Hb = H + (size_t)b*NNODE*DF;
  float accv = 0.f;
  int s2 = pg;
  for (; s2+24 < KSEL; s2 += 32){
    int i0=selidx[s2], i1=selidx[s2+8], i2=selidx[s2+16], i3=selidx[s2+24];
    float w0=selval[s2], w1=selval[s2+8], w2=selval[s2+16], w3=selval[s2+24];
    float v0=Hb[(size_t)i0*DF+f], v1=Hb[(size_t)i1*DF+f],
          v2=Hb[(size_t)i2*DF+f], v3=Hb[(size_t)i3*DF+f];
    accv += w0*v0 + w1*v1 + w2*v2 + w3*v3;
  }
  for (; s2<KSEL; s2+=8) accv += selval[s2]*Hb[(size_t)selidx[s2]*DF+f];
  part[pg*DF + f] = accv;
  __syncthreads();
  if (t < DF){
    float e = 0.f;
    for (int g2=0; g2<8; ++g2) e += part[g2*DF + t];
    emb[t] = e / (float)KSEL;
  }
  __syncthreads();
  if (t < DF){
    float hv = bc1[t];
    const float* wr = Wc1 + t*DF;
    for (int f2=0; f2<DF; ++f2) hv = fmaf(emb[f2], wr[f2], hv);
    hred[t] = fmaxf(hv, 0.f) * Wc2[t];
  }
  __syncthreads();
  if (t == 0){
    float o = bc2[0];
    for (int c2=0; c2<DF; ++c2) o += hred[c2];
    out[b] = o;
  }
}

// ---------------- launch ----------------
extern "C" void kernel_launch(void* const* d_in, const int* in_sizes, int n_in,
                              void* d_out, int out_size, void* d_ws, size_t ws_size,
                              hipStream_t stream)
{
  (void)in_sizes; (void)n_in; (void)out_size; (void)ws_size;
  const float* x   = (const float*)d_in[0];
  const int* esrc  = (const int*)d_in[1];
  const int* edst  = (const int*)d_in[2];
  const float* Wl1 = (const float*)d_in[3];
  const float* bl1 = (const float*)d_in[4];
  const float* Wr1 = (const float*)d_in[5];
  const float* Wl2 = (const float*)d_in[6];
  const float* bl2 = (const float*)d_in[7];
  const float* Wr2 = (const float*)d_in[8];
  const float* pw  = (const float*)d_in[9];
  const float* Wc1 = (const float*)d_in[10];
  const float* bc1 = (const float*)d_in[11];
  const float* Wc2 = (const float*)d_in[12];
  const float* bc2 = (const float*)d_in[13];
  float* out = (float*)d_out;

  char* ws = (char*)d_ws;                       // ~68 MB used
  float*    H1     = (float*)   (ws + 0);          // 32MB
  float*    H2     = (float*)   (ws + 33554432);   // 32MB
  uint32_t* deg    = (uint32_t*)(ws + 67108864);   // 256KB
  uint32_t* rowptr = (uint32_t*)(ws + 67371008);   // 65537 u32
  unsigned short* colh = (unsigned short*)(ws + 67633408); // 1MB u16
  float*    scores = (float*)   (ws + 68681728);   // 256KB
  unsigned short* Bpk = (unsigned short*)(ws + 68944128); // 256KB (2 layers)

  hipMemsetAsync(deg, 0, NT*sizeof(uint32_t), stream);

  // degree count (blocks 0..2047) + weight pack (blocks 2048..2079)
  k_deg    <<<ETOT/256 + 32, 256, 0, stream>>>(edst, deg, Wl1, Wr1, Wl2, Wr2, Bpk);
  k_scanG  <<<NB, 256, 0, stream>>>(deg, rowptr);
  k_scatter<<<ETOT/256, 256, 0, stream>>>(esrc, edst, rowptr, deg, colh);

  // fused layers: global_load_lds gather + mean + GEMM per block
  k_sage<1><<<NT/32, 128, 0, stream>>>(x,  rowptr, colh, Bpk,         bl1,
                                       H1, nullptr, nullptr);
  k_sage<2><<<NT/32, 128, 0, stream>>>(H1, rowptr, colh, Bpk + 65536, bl2,
                                       H2, pw, scores);

  k_topk<<<NB, 1024, 0, stream>>>(scores, H2, Wc1, bc1, Wc2, bc2, out);
}

// Round 17
// 153.285 us; speedup vs baseline: 2.0358x; 2.0358x over previous
//
#include <hip/hip_runtime.h>
#include <stdint.h>
#include <math.h>

// Problem constants (fixed by the reference)
#define NB    32          // graphs
#define NNODE 2048        // nodes per graph
#define EPB   16384       // edges per graph
#define NT    (NB*NNODE)  // 65536 total nodes
#define ETOT  (NB*EPB)    // 524288 edges
#define DF    128         // feature dim
#define KSEL  615         // ceil(0.3*2048)
#define EMAX  512         // LDS-staged edge cap per 32-row tile (mean 256)

typedef __attribute__((ext_vector_type(8))) short bf16x8;
typedef __attribute__((ext_vector_type(4))) float f32x4;

// ---- split-precision helpers: f32 ~= hi(bf16) + lo(bf16), err ~2^-17 ----
__device__ __forceinline__ unsigned short f2bf(float f){
  uint32_t u = __float_as_uint(f);
  u += 0x7FFFu + ((u>>16)&1u);                 // RNE
  return (unsigned short)(u>>16);
}
__device__ __forceinline__ void split2(float f, unsigned short& hi, unsigned short& lo){
  unsigned short h = f2bf(f);
  float fh = __uint_as_float(((uint32_t)h)<<16);
  hi = h;
  lo = f2bf(f - fh);
}
// monotone u32 <-> f32 (ascending u32 == ascending float over all reals)
__device__ __forceinline__ uint32_t f2mono(float f){
  uint32_t u = __float_as_uint(f);
  return (u & 0x80000000u) ? ~u : (u | 0x80000000u);
}
__device__ __forceinline__ float mono2f(uint32_t m){
  uint32_t u = (m & 0x80000000u) ? (m ^ 0x80000000u) : ~m;
  return __uint_as_float(u);
}

// ---------------- CSR build ----------------
// blocks 0..2047: degree count (global atomics). blocks 2048..2079: packB.
__global__ void k_deg(const int* __restrict__ edst, uint32_t* __restrict__ deg,
                      const float* __restrict__ Wl1, const float* __restrict__ Wr1,
                      const float* __restrict__ Wl2, const float* __restrict__ Wr2,
                      unsigned short* __restrict__ Bpk){
  const int bid = blockIdx.x;
  if (bid < ETOT/256){
    int e = bid*256 + threadIdx.x;
    int g = e >> 14;                           // EPB = 2^14
    atomicAdd(&deg[g*NNODE + edst[e]], 1u);
  } else {
    // weight pack: Bpk elem offset ks*8192 + ct*1024 + part*512 + lane*8 + j
    int tt = (bid - ETOT/256)*256 + threadIdx.x;   // 0..8191
    int layer = tt >> 12;
    int t2 = tt & 4095;
    const float* Wl = layer ? Wl2 : Wl1;
    const float* Wr = layer ? Wr2 : Wr1;
    unsigned short* B = Bpk + (size_t)layer*65536;
    int lane = t2 & 63;
    int ct   = (t2>>6) & 7;
    int ks   = (t2>>9) & 7;
    int c  = ct*16 + (lane & 15);
    int k0 = ks*32 + ((lane>>4)<<3);
    size_t base = ((size_t)((ks*8+ct)*2)*64 + lane)*8;
    #pragma unroll
    for (int j=0;j<8;++j){
      int k = k0 + j;
      float v = (k < DF) ? Wl[c*DF + k] : Wr[c*DF + (k-DF)];
      unsigned short h, l; split2(v, h, l);
      B[base + j]       = h;
      B[base + 512 + j] = l;
    }
  }
}

// per-graph exclusive scan of degrees (graphs independent: g*EPB base)
__global__ __launch_bounds__(256) void k_scanG(const uint32_t* __restrict__ deg,
                                               uint32_t* __restrict__ rowptr){
  __shared__ uint32_t wsum4[4];
  const int g = blockIdx.x, t = threadIdx.x;
  const int lane = t & 63, wid = t >> 6;
  const uint32_t* dg = deg + g*NNODE;
  uint32_t v[8]; const int b8 = t*8;
  uint32_t tsum = 0;
  #pragma unroll
  for (int j=0;j<8;++j){ v[j] = dg[b8+j]; tsum += v[j]; }
  uint32_t x = tsum;
  #pragma unroll
  for (int off=1; off<64; off<<=1){
    uint32_t y = __shfl_up(x, off, 64);
    if (lane >= off) x += y;
  }
  if (lane == 63) wsum4[wid] = x;
  __syncthreads();
  if (t == 0){
    uint32_t a = 0;
    #pragma unroll
    for (int w=0; w<4; ++w){ uint32_t tmp=wsum4[w]; wsum4[w]=a; a+=tmp; }
  }
  __syncthreads();
  uint32_t run = wsum4[wid] + x - tsum;        // thread-exclusive start
  uint32_t* rp = rowptr + g*NNODE + b8;
  #pragma unroll
  for (int j=0;j<8;++j){ rp[j] = g*EPB + run; run += v[j]; }
  if (g == 0 && t == 0) rowptr[NT] = ETOT;
}

// scatter edges into CSR order; col stored as u16 LOCAL node id
__global__ void k_scatter(const int* __restrict__ esrc, const int* __restrict__ edst,
                          const uint32_t* __restrict__ rowptr, uint32_t* __restrict__ deg,
                          unsigned short* __restrict__ colh){
  int e = blockIdx.x*256 + threadIdx.x;
  int g = e >> 14;
  int d = g*NNODE + edst[e];
  uint32_t old = atomicSub(&deg[d], 1u);
  colh[rowptr[d] + old - 1u] = (unsigned short)esrc[e];
}

// ---------------- fused SAGE layer: pipelined gather + split-bf16 MFMA -----
// 128 threads, 32 rows/block (r11's proven 49us structure). Phase 0: stage
// CSR slice (u16 col) to LDS. Phase 1: streaming gather — each 32-lane group
// owns a contiguous 8-row CSR segment, register double-buffer (16 loads in
// flight), flush to LDS on row change. Phase 2: 2 waves x 16 rows, K=256
// (ks0-3 agg from LDS, ks4-7 own row), 3 MFMAs per (ct,ks).
// XCD swizzle: graph = bid&31.
template<int LAYER>
__global__ __launch_bounds__(128, 4) void k_sage(
    const float* __restrict__ Xin, const uint32_t* __restrict__ rowptr,
    const unsigned short* __restrict__ colh, const unsigned short* __restrict__ Bpk,
    const float* __restrict__ bias, float* __restrict__ OUT,
    const float* __restrict__ pw, float* __restrict__ scores)
{
  __shared__ float smemA[32][132];             // 16.9KB, +4 float pad per row
  __shared__ unsigned short lcol[EMAX];        // 1KB staged local edge ids
  __shared__ uint32_t lrpl[33];                // tile-relative rowptr

  const int t = threadIdx.x;
  const int g = blockIdx.x & 31, jb = blockIdx.x >> 5;   // 64 blocks/graph
  const int rowBase = g*NNODE + jb*32;
  const float* Xg = Xin + (size_t)(g*NNODE)*DF;          // graph-local rows

  // ---- phase 0: stage CSR slice ----
  const uint32_t e0 = rowptr[rowBase];
  if (t < 33) lrpl[t] = rowptr[rowBase + t] - e0;
  const int ecnt = (int)(rowptr[rowBase + 32] - e0);
  for (int i=t; i<ecnt && i<EMAX; i+=128) lcol[i] = colh[e0+i];
  __syncthreads();

  // ---- phase 1: streaming pipelined gather ----
  {
    const int grp = t >> 5, c = t & 31;
    int cur = grp*8;                           // local row being accumulated
    const int curEnd = grp*8 + 8;
    f32x4 accv = {0.f,0.f,0.f,0.f};

    auto flushrow = [&](){
      uint32_t d = lrpl[cur+1] - lrpl[cur];
      float invd = 1.0f / (float)(d ? d : 1u);
      *(f32x4*)&smemA[cur][4*c] = accv * invd;
      accv = (f32x4){0.f,0.f,0.f,0.f};
      cur++;
    };

    const uint32_t kb = lrpl[grp*8], ke = lrpl[curEnd];
    auto run = [&](auto colAt){
      f32x4 v[8], w[8];
      #pragma unroll
      for (int j=0;j<8;++j){
        uint32_t kk = kb + j;
        int s = colAt(kk < ke ? kk : kb);
        v[j] = *(const f32x4*)(Xg + (size_t)s*DF + 4*c);
      }
      for (uint32_t k = kb; k < ke; k += 8){
        #pragma unroll
        for (int j=0;j<8;++j){                 // issue next chunk
          uint32_t kk = k + 8 + j;
          int s = colAt(kk < ke ? kk : k);
          w[j] = *(const f32x4*)(Xg + (size_t)s*DF + 4*c);
        }
        #pragma unroll
        for (int j=0;j<8;++j){                 // reduce current chunk
          uint32_t kk = k + j;
          if (kk < ke){
            while (lrpl[cur+1] <= kk) flushrow();
            accv += v[j];
          }
        }
        #pragma unroll
        for (int j=0;j<8;++j) v[j] = w[j];
      }
    };
    if (kb < ke){
      if (ecnt <= EMAX) run([&](uint32_t k){ return (int)lcol[k]; });
      else              run([&](uint32_t k){ return (int)colh[e0+k]; });
    }
    while (cur < curEnd) flushrow();           // trailing (incl. empty) rows
  }
  __syncthreads();

  // ---- phase 2: MFMA ----
  const int l = t & 63, wid = t >> 6;
  const int q = l >> 4, c16 = l & 15;
  const int arow = rowBase + wid*16 + c16;

  f32x4 own[8];                                // own row ks4..7 (issue early)
  #pragma unroll
  for (int ks4=0; ks4<4; ++ks4){
    const float* s = Xin + (size_t)arow*DF + ks4*32 + q*8;
    own[ks4*2]   = *(const f32x4*)s;
    own[ks4*2+1] = *(const f32x4*)(s+4);
  }

  f32x4 acc[8];
  #pragma unroll
  for (int ct=0; ct<8; ++ct) acc[ct] = (f32x4){0.f,0.f,0.f,0.f};

  #pragma unroll
  for (int ks=0; ks<8; ++ks){
    f32x4 A0, A1;
    if (ks < 4){
      const float* s = &smemA[wid*16 + c16][ks*32 + q*8];
      A0 = *(const f32x4*)s; A1 = *(const f32x4*)(s+4);
    } else {
      A0 = own[(ks-4)*2]; A1 = own[(ks-4)*2+1];
    }
    float v[8] = {A0.x,A0.y,A0.z,A0.w,A1.x,A1.y,A1.z,A1.w};
    bf16x8 ahi, alo;
    #pragma unroll
    for (int j=0;j<8;++j){
      unsigned short h, lo_; split2(v[j], h, lo_);
      ahi[j] = (short)h; alo[j] = (short)lo_;
    }
    const unsigned short* bp = Bpk + (size_t)ks*8192 + l*8;
    #pragma unroll
    for (int ct=0; ct<8; ++ct){
      bf16x8 bhi = *(const bf16x8*)(bp + ct*1024);
      bf16x8 blo = *(const bf16x8*)(bp + ct*1024 + 512);
      acc[ct] = __builtin_amdgcn_mfma_f32_16x16x32_bf16(ahi, bhi, acc[ct], 0,0,0);
      acc[ct] = __builtin_amdgcn_mfma_f32_16x16x32_bf16(ahi, blo, acc[ct], 0,0,0);
      acc[ct] = __builtin_amdgcn_mfma_f32_16x16x32_bf16(alo, bhi, acc[ct], 0,0,0);
    }
  }

  // ---- epilogue ----
  const int rowOut = rowBase + wid*16;
  if constexpr (LAYER==1){
    #pragma unroll
    for (int ct=0; ct<8; ++ct){
      int c = ct*16 + c16;
      float bv = bias[c];
      #pragma unroll
      for (int r=0; r<4; ++r){
        int grow = rowOut + q*4 + r;
        OUT[(size_t)grow*DF + c] = fmaxf(acc[ct][r] + bv, 0.f);
      }
    }
  } else {
    float ov[8][4];
    float pwv[8];
    float n2 = 0.f;
    #pragma unroll
    for (int ct=0; ct<8; ++ct){ pwv[ct] = pw[ct*16 + c16]; n2 += pwv[ct]*pwv[ct]; }
    n2 += __shfl_xor(n2,8,16); n2 += __shfl_xor(n2,4,16);
    n2 += __shfl_xor(n2,2,16); n2 += __shfl_xor(n2,1,16);
    float nrm = sqrtf(n2);
    #pragma unroll
    for (int ct=0; ct<8; ++ct){
      int c = ct*16 + c16;
      float bv = bias[c];
      #pragma unroll
      for (int r=0; r<4; ++r){
        int grow = rowOut + q*4 + r;
        float o = fmaxf(acc[ct][r] + bv, 0.f);
        OUT[(size_t)grow*DF + c] = o;
        ov[ct][r] = o;
      }
    }
    #pragma unroll
    for (int r=0; r<4; ++r){
      float p = 0.f;
      #pragma unroll
      for (int ct=0; ct<8; ++ct) p += ov[ct][r]*pwv[ct];
      p += __shfl_xor(p,8,16); p += __shfl_xor(p,4,16);
      p += __shfl_xor(p,2,16); p += __shfl_xor(p,1,16);
      if (c16 == 0) scores[rowOut + q*4 + r] = tanhf(p/nrm);
    }
  }
}

// ---------------- top-k via radix-select + pool + classifier ---------------
__global__ __launch_bounds__(1024) void k_topk(
    const float* __restrict__ scores, const float* __restrict__ H,
    const float* __restrict__ Wc1, const float* __restrict__ bc1,
    const float* __restrict__ Wc2, const float* __restrict__ bc2,
    float* __restrict__ out)
{
  __shared__ uint32_t keys[NNODE];            // 8KB monotone keys
  __shared__ uint32_t hist[64];
  __shared__ uint32_t wsum[16];               // block-scan wave sums
  __shared__ uint32_t sh_b, sh_rank, sh_cnt;
  __shared__ unsigned short selidx[KSEL+1];
  __shared__ float selval[KSEL+1];
  __shared__ float part[8*DF];
  __shared__ float emb[DF];
  __shared__ float hred[DF];

  const int t = threadIdx.x; const int b = blockIdx.x;
  const int lane = t & 63, wid = t >> 6;
  const float* sc = scores + b*NNODE;

  for (int i=t; i<NNODE; i+=1024) keys[i] = f2mono(sc[i]);
  __syncthreads();

  // ---- radix select: find threshold key T = 615th largest ----
  uint32_t prefix = 0, prefmask = 0, rank = KSEL, cntT = 0;
  #pragma unroll
  for (int lev=0; lev<6; ++lev){
    const int shift = (lev<5) ? (26 - 6*lev) : 0;
    const uint32_t bmask = (lev<5) ? 63u : 3u;
    if (t < 64) hist[t] = 0;
    __syncthreads();
    for (int i=t; i<NNODE; i+=1024){
      uint32_t k = keys[i];
      if ((k & prefmask) == prefix) atomicAdd(&hist[(k>>shift)&bmask], 1u);
    }
    __syncthreads();
    if (t < 64){
      uint32_t x = hist[t];
      #pragma unroll
      for (int off=1; off<64; off<<=1){        // inclusive suffix sum
        uint32_t y = __shfl_down(x, off, 64);
        if (t + off < 64) x += y;
      }
      uint32_t above = __shfl_down(x, 1, 64);
      if (t == 63) above = 0;
      if (above < rank && rank <= x){
        sh_b = (uint32_t)t; sh_rank = rank - above; sh_cnt = x - above;
      }
    }
    __syncthreads();
    prefix |= (sh_b << shift);
    prefmask |= (bmask << shift);
    rank = sh_rank; cntT = sh_cnt;
    __syncthreads();
  }
  const uint32_t T = prefix;
  const uint32_t m = rank;

  // ---- selection + compaction (block scans, shfl-based) ----
  uint32_t k0 = keys[2*t], k1 = keys[2*t+1];
  uint32_t eq0 = (k0 == T), eq1 = (k1 == T);
  uint32_t eqr0 = 0, eqr1 = 0;

  if (m != cntT){
    uint32_t v = eq0 + eq1, x = v;
    #pragma unroll
    for (int off=1; off<64; off<<=1){
      uint32_t y = __shfl_up(x, off, 64);
      if (lane >= off) x += y;
    }
    if (lane == 63) wsum[wid] = x;
    __syncthreads();
    if (wid == 0){
      uint32_t s = (lane < 16) ? wsum[lane] : 0;
      #pragma unroll
      for (int off=1; off<16; off<<=1){
        uint32_t y = __shfl_up(s, off, 64);
        if (lane >= off) s += y;
      }
      if (lane < 16) wsum[lane] = s;
    }
    __syncthreads();
    uint32_t excl = (wid ? wsum[wid-1] : 0) + x - v;
    eqr0 = excl; eqr1 = excl + eq0;
    __syncthreads();
  }

  uint32_t sel0 = (k0 > T) || (eq0 && eqr0 < m);
  uint32_t sel1 = (k1 > T) || (eq1 && eqr1 < m);
  {
    uint32_t v = sel0 + sel1, x = v;
    #pragma unroll
    for (int off=1; off<64; off<<=1){
      uint32_t y = __shfl_up(x, off, 64);
      if (lane >= off) x += y;
    }
    if (lane == 63) wsum[wid] = x;
    __syncthreads();
    if (wid == 0){
      uint32_t s = (lane < 16) ? wsum[lane] : 0;
      #pragma unroll
      for (int off=1; off<16; off<<=1){
        uint32_t y = __shfl_up(s, off, 64);
        if (lane >= off) s += y;
      }
      if (lane < 16) wsum[lane] = s;
    }
    __syncthreads();
    uint32_t excl = (wid ? wsum[wid-1] : 0) + x - v;
    if (sel0){ selidx[excl] = (unsigned short)(2*t);   selval[excl] = mono2f(k0); }
    if (sel1){ selidx[excl+sel0] = (unsigned short)(2*t+1); selval[excl+sel0] = mono2f(k1); }
  }
  __syncthreads();

  // ---- gated mean over the 615 selected rows (4-deep unrolled gather) ----
  const int pg = t >> 7, f = t & (DF-1);
  const float* Hb = H + (size_t)b*NNODE*DF;
  float accv = 0.f;
  int s2 = pg;
  for (; s2+24 < KSEL; s2 += 32){
    int i0=selidx[s2], i1=selidx[s2+8], i2=selidx[s2+16], i3=selidx[s2+24];
    float w0=selval[s2], w1=selval[s2+8], w2=selval[s2+16], w3=selval[s2+24];
    float v0=Hb[(size_t)i0*DF+f], v1=Hb[(size_t)i1*DF+f],
          v2=Hb[(size_t)i2*DF+f], v3=Hb[(size_t)i3*DF+f];
    accv += w0*v0 + w1*v1 + w2*v2 + w3*v3;
  }
  for (; s2<KSEL; s2+=8) accv += selval[s2]*Hb[(size_t)selidx[s2]*DF+f];
  part[pg*DF + f] = accv;
  __syncthreads();
  if (t < DF){
    float e = 0.f;
    for (int g2=0; g2<8; ++g2) e += part[g2*DF + t];
    emb[t] = e / (float)KSEL;
  }
  __syncthreads();
  if (t < DF){
    float hv = bc1[t];
    const float* wr = Wc1 + t*DF;
    for (int f2=0; f2<DF; ++f2) hv = fmaf(emb[f2], wr[f2], hv);
    hred[t] = fmaxf(hv, 0.f) * Wc2[t];
  }
  __syncthreads();
  if (t == 0){
    float o = bc2[0];
    for (int c2=0; c2<DF; ++c2) o += hred[c2];
    out[b] = o;
  }
}

// ---------------- launch ----------------
extern "C" void kernel_launch(void* const* d_in, const int* in_sizes, int n_in,
                              void* d_out, int out_size, void* d_ws, size_t ws_size,
                              hipStream_t stream)
{
  (void)in_sizes; (void)n_in; (void)out_size; (void)ws_size;
  const float* x   = (const float*)d_in[0];
  const int* esrc  = (const int*)d_in[1];
  const int* edst  = (const int*)d_in[2];
  const float* Wl1 = (const float*)d_in[3];
  const float* bl1 = (const float*)d_in[4];
  const float* Wr1 = (const float*)d_in[5];
  const float* Wl2 = (const float*)d_in[6];
  const float* bl2 = (const float*)d_in[7];
  const float* Wr2 = (const float*)d_in[8];
  const float* pw  = (const float*)d_in[9];
  const float* Wc1 = (const float*)d_in[10];
  const float* bc1 = (const float*)d_in[11];
  const float* Wc2 = (const float*)d_in[12];
  const float* bc2 = (const float*)d_in[13];
  float* out = (float*)d_out;

  char* ws = (char*)d_ws;                       // ~68 MB used
  float*    H1     = (float*)   (ws + 0);          // 32MB
  float*    H2     = (float*)   (ws + 33554432);   // 32MB
  uint32_t* deg    = (uint32_t*)(ws + 67108864);   // 256KB
  uint32_t* rowptr = (uint32_t*)(ws + 67371008);   // 65537 u32
  unsigned short* colh = (unsigned short*)(ws + 67633408); // 1MB u16
  float*    scores = (float*)   (ws + 68681728);   // 256KB
  unsigned short* Bpk = (unsigned short*)(ws + 68944128); // 256KB (2 layers)

  hipMemsetAsync(deg, 0, NT*sizeof(uint32_t), stream);

  // degree count (blocks 0..2047) + weight pack (blocks 2048..2079)
  k_deg    <<<ETOT/256 + 32, 256, 0, stream>>>(edst, deg, Wl1, Wr1, Wl2, Wr2, Bpk);
  k_scanG  <<<NB, 256, 0, stream>>>(deg, rowptr);
  k_scatter<<<ETOT/256, 256, 0, stream>>>(esrc, edst, rowptr, deg, colh);

  // fused layers: pipelined gather + mean + GEMM per block (r11 structure)
  k_sage<1><<<NT/32, 128, 0, stream>>>(x,  rowptr, colh, Bpk,         bl1,
                                       H1, nullptr, nullptr);
  k_sage<2><<<NT/32, 128, 0, stream>>>(H1, rowptr, colh, Bpk + 65536, bl2,
                                       H2, pw, scores);

  k_topk<<<NB, 1024, 0, stream>>>(scores, H2, Wc1, bc1, Wc2, bc2, out);
}